// Round 4
// baseline (12116.658 us; speedup 1.0000x reference)
//
#include <hip/hip_runtime.h>
#include <hip/hip_bf16.h>

// LSTM T=4096, B=16, I=64, H=256 (4H=1024 gate rows), O=1.
//
// R4: 16 WGs x 256 threads (1 wave/SIMD -> 512-reg unified tier).
// Thread tid owns ALL FOUR gate rows of hidden unit tid:
//   i=tid, f=tid+256, g=tid+512, o=tid+768.
//  - halves LDS h-broadcast traffic vs R3 (rows/thread 2->4)
//  - no cross-thread gate exchange; ONE barrier/step (double-buffered h)
//  - W_hh fp16: 116 pairs/row x 4 rows = 464 f16x2 in regs (256 arch + AGPR),
//    12 pairs/row tail in 48 KB LDS as [chunk][row] f16x8 (conflict-free,
//    verified 0 bank conflicts in R3 with same layout).
//  - x@W_ih precomputed to fp16 xg in d_ws (kernel A), prefetched 1 step ahead.

typedef _Float16 f16x2 __attribute__((ext_vector_type(2)));
typedef _Float16 f16x8 __attribute__((ext_vector_type(8)));

#define T_STEPS 4096
#define BATCH   16
#define IN      64
#define HID     256
#define G4      1024
#define REG_PAIRS 116   // f16x2 pairs per row in VGPRs
#define NCHUNK    29    // REG_PAIRS/4 f16x8 h-chunks
#define TAILCH    3     // LDS tail chunks (12 pairs; 116+12=128)

__device__ __forceinline__ float fdot2(f16x2 a, f16x2 b, float c) {
#if __has_builtin(__builtin_amdgcn_fdot2)
    return __builtin_amdgcn_fdot2(a, b, c, false);
#else
    return c + (float)a.x * (float)b.x + (float)a.y * (float)b.y;
#endif
}

__device__ __forceinline__ float sigf(float x) {
    return 1.0f / (1.0f + __expf(-x));
}
__device__ __forceinline__ float tanh_fast(float x) {
    return 2.0f * sigf(2.0f * x) - 1.0f;
}

// ---------------- Kernel A: x_gates precompute ----------------
__global__ __launch_bounds__(256) void xg_precompute(
    const float* __restrict__ x, const float* __restrict__ W_ih,
    const float* __restrict__ b_ih, const float* __restrict__ b_hh,
    _Float16* __restrict__ xg)
{
    const int b   = blockIdx.x;
    const int t0  = blockIdx.y * 128;
    const int tid = threadIdx.x;

    __shared__ __align__(16) f16x2 xs2[IN / 2];

    f16x2 wih[4][32];
    float bias[4];
    const float2* W2 = (const float2*)W_ih;
    #pragma unroll
    for (int g = 0; g < 4; ++g) {
        const int r = tid + g * 256;
        #pragma unroll
        for (int m = 0; m < 32; ++m) {
            float2 v = W2[r * 32 + m];
            wih[g][m] = f16x2{(_Float16)v.x, (_Float16)v.y};
        }
        bias[g] = b_ih[r] + b_hh[r];
    }

    for (int tt = 0; tt < 128; ++tt) {
        const int t = t0 + tt;
        if (tid < 32) {
            float2 v = ((const float2*)x)[(t * BATCH + b) * 32 + tid];
            xs2[tid] = f16x2{(_Float16)v.x, (_Float16)v.y};
        }
        __syncthreads();
        float acc[4] = {bias[0], bias[1], bias[2], bias[3]};
        #pragma unroll
        for (int m = 0; m < 32; ++m) {
            f16x2 xv = xs2[m];
            #pragma unroll
            for (int g = 0; g < 4; ++g) acc[g] = fdot2(wih[g][m], xv, acc[g]);
        }
        #pragma unroll
        for (int g = 0; g < 4; ++g)
            xg[(t * BATCH + b) * G4 + g * 256 + tid] = (_Float16)acc[g];
        __syncthreads();
    }
}

// ---------------- Kernel B: persistent recurrence ----------------
template <bool PRE>
__global__ __launch_bounds__(256, 1) void lstm_rec(
    const float* __restrict__ x,     const float* __restrict__ W_ih,
    const float* __restrict__ W_hh,  const float* __restrict__ b_ih,
    const float* __restrict__ b_hh,  const float* __restrict__ W_lin,
    const float* __restrict__ b_lin, const float* __restrict__ h0,
    const float* __restrict__ c0,    const _Float16* __restrict__ xg,
    float* __restrict__ out)
{
    const int b   = blockIdx.x;
    const int tid = threadIdx.x;   // hidden unit index 0..255

    __shared__ __align__(16) f16x8 wt8[TAILCH * 1024];  // 48 KB tail weights
    __shared__ __align__(16) f16x8 hb8[2][32];          // h double buffer, 1 KB
    __shared__ float esh[256];                          // epilogue
    __shared__ float xsf[IN];                           // fallback x staging

    // ---- one-time: W_hh -> fp16 regs (4 rows x 116 pairs) + LDS tail ----
    f16x2 wr[4][REG_PAIRS];
    const float4* Wh4 = (const float4*)W_hh;            // 2 pairs per float4
    #pragma unroll
    for (int g = 0; g < 4; ++g) {
        const int r = tid + g * 256;
        #pragma unroll
        for (int q = 0; q < REG_PAIRS / 2; ++q) {       // 58 float4 = 116 pairs
            float4 v = Wh4[r * 64 + q];
            wr[g][2 * q]     = f16x2{(_Float16)v.x, (_Float16)v.y};
            wr[g][2 * q + 1] = f16x2{(_Float16)v.z, (_Float16)v.w};
        }
        #pragma unroll
        for (int c = 0; c < TAILCH; ++c) {              // pairs 116..127
            union { f16x8 v; f16x2 p[4]; } u;
            float4 a = Wh4[r * 64 + 58 + c * 2];
            float4 d = Wh4[r * 64 + 58 + c * 2 + 1];
            u.p[0] = f16x2{(_Float16)a.x, (_Float16)a.y};
            u.p[1] = f16x2{(_Float16)a.z, (_Float16)a.w};
            u.p[2] = f16x2{(_Float16)d.x, (_Float16)d.y};
            u.p[3] = f16x2{(_Float16)d.z, (_Float16)d.w};
            wt8[c * 1024 + r] = u.v;
        }
    }

    float bias[4] = {0.f, 0.f, 0.f, 0.f};
    if (!PRE) {
        #pragma unroll
        for (int g = 0; g < 4; ++g)
            bias[g] = b_ih[tid + g * 256] + b_hh[tid + g * 256];
    }

    // ---- state ----
    float cst  = c0[b * HID + tid];
    float hval = h0[b * HID + tid];
    ((_Float16*)hb8[0])[tid] = (_Float16)hval;

    float xgc[4] = {0.f, 0.f, 0.f, 0.f};
    float xnext = 0.0f;
    if (PRE) {
        #pragma unroll
        for (int g = 0; g < 4; ++g)
            xgc[g] = (float)xg[b * G4 + g * 256 + tid];
    } else {
        if (tid < IN) xnext = x[b * IN + tid];
    }

    for (int t = 0; t < T_STEPS; ++t) {
        __syncthreads();  // h(t) in hb8[t&1] visible
        const f16x8* hb = hb8[t & 1];

        float acc[4];
        float xgn[4] = {0.f, 0.f, 0.f, 0.f};
        if (PRE) {
            if (t + 1 < T_STEPS) {   // prefetch next step's x-gates
                #pragma unroll
                for (int g = 0; g < 4; ++g)
                    xgn[g] = (float)xg[((t + 1) * BATCH + b) * G4 + g * 256 + tid];
            }
            #pragma unroll
            for (int g = 0; g < 4; ++g) acc[g] = xgc[g];
        } else {
            if (tid < IN) xsf[tid] = xnext;
            __syncthreads();
            if (tid < IN && t + 1 < T_STEPS)
                xnext = x[((t + 1) * BATCH + b) * IN + tid];
            #pragma unroll
            for (int g = 0; g < 4; ++g) acc[g] = bias[g];
            const float4* W4 = (const float4*)W_ih;
            #pragma unroll
            for (int ic = 0; ic < 16; ++ic) {
                #pragma unroll
                for (int g = 0; g < 4; ++g) {
                    float4 wv = W4[(tid + g * 256) * 16 + ic];
                    acc[g] += wv.x * xsf[ic*4] + wv.y * xsf[ic*4+1]
                            + wv.z * xsf[ic*4+2] + wv.w * xsf[ic*4+3];
                }
            }
        }

        // ---- h . W_hh : 29 register chunks ----
        #pragma unroll
        for (int cc = 0; cc < NCHUNK; ++cc) {
            union { f16x8 v; f16x2 p[4]; } hu;
            hu.v = hb[cc];
            #pragma unroll
            for (int u = 0; u < 4; ++u) {
                #pragma unroll
                for (int g = 0; g < 4; ++g)
                    acc[g] = fdot2(wr[g][cc * 4 + u], hu.p[u], acc[g]);
            }
        }
        // ---- 3 LDS tail chunks ----
        #pragma unroll
        for (int c = 0; c < TAILCH; ++c) {
            union { f16x8 v; f16x2 p[4]; } hu, wa[4];
            hu.v = hb[NCHUNK + c];
            #pragma unroll
            for (int g = 0; g < 4; ++g) wa[g].v = wt8[c * 1024 + tid + g * 256];
            #pragma unroll
            for (int u = 0; u < 4; ++u) {
                #pragma unroll
                for (int g = 0; g < 4; ++g)
                    acc[g] = fdot2(wa[g].p[u], hu.p[u], acc[g]);
            }
        }

        // ---- gates: all four local to this thread ----
        float gi = sigf(acc[0]);
        float gf = sigf(acc[1]);
        float gg = tanh_fast(acc[2]);
        float go = sigf(acc[3]);
        cst  = gf * cst + gi * gg;
        hval = go * tanh_fast(cst);
        ((_Float16*)hb8[(t + 1) & 1])[tid] = (_Float16)hval;

        if (PRE) {
            #pragma unroll
            for (int g = 0; g < 4; ++g) xgc[g] = xgn[g];
        }
    }

    // ---- epilogue: y[b] = sigmoid(h . W_lin + b_lin) ----
    esh[tid] = hval * W_lin[tid];
    __syncthreads();
    if (tid == 0) {
        float z = b_lin[0];
        for (int n = 0; n < 256; ++n) z += esh[n];
        out[b] = sigf(z);
    }
}

extern "C" void kernel_launch(void* const* d_in, const int* in_sizes, int n_in,
                              void* d_out, int out_size, void* d_ws, size_t ws_size,
                              hipStream_t stream) {
    const float* x     = (const float*)d_in[0];
    const float* W_ih  = (const float*)d_in[1];
    const float* W_hh  = (const float*)d_in[2];
    const float* b_ih  = (const float*)d_in[3];
    const float* b_hh  = (const float*)d_in[4];
    const float* W_lin = (const float*)d_in[5];
    const float* b_lin = (const float*)d_in[6];
    const float* h0    = (const float*)d_in[7];
    const float* c0    = (const float*)d_in[8];
    float* out = (float*)d_out;

    const size_t need = (size_t)T_STEPS * BATCH * G4 * sizeof(_Float16); // 128 MB
    if (ws_size >= need) {
        _Float16* xg = (_Float16*)d_ws;
        xg_precompute<<<dim3(BATCH, 32), 256, 0, stream>>>(x, W_ih, b_ih, b_hh, xg);
        lstm_rec<true><<<dim3(BATCH), 256, 0, stream>>>(
            x, W_ih, W_hh, b_ih, b_hh, W_lin, b_lin, h0, c0, xg, out);
    } else {
        lstm_rec<false><<<dim3(BATCH), 256, 0, stream>>>(
            x, W_ih, W_hh, b_ih, b_hh, W_lin, b_lin, h0, c0,
            (const _Float16*)nullptr, out);
    }
}

// Round 5
// 9331.763 us; speedup vs baseline: 1.2984x; 1.2984x over previous
//
#include <hip/hip_runtime.h>
#include <hip/hip_bf16.h>

// LSTM T=4096, B=16, I=64, H=256 (4H=1024 gate rows), O=1.
//
// R5: 16 WGs x 1024 threads (16 waves -> 4 waves/SIMD, 128-reg tier).
// Thread = (unit j = tid>>2, k-quarter q = tid&3): owns all 4 gate rows of
// unit j over k in [64q, 64q+64).
//  - weights: 24 f16x2 pairs/row in VGPRs (96 regs) + 8 pairs/row in dynamic
//    LDS (128 KB). Working set ~28 regs -> fits 128-cap, no AGPR/scratch.
//  - h-broadcast: 8 ds_read_b128 per thread (its quarter only).
//  - quad shfl_xor(1,2) reduce -> q=0 lane has complete i,f,g,o for unit j:
//    ONE barrier/step, gates fully thread-local.
//  - xg precomputed TRANSPOSED [t][b][unit*4+gate] fp16 -> q=0 loads 1 b64.

typedef _Float16 f16x2 __attribute__((ext_vector_type(2)));
typedef _Float16 f16x4 __attribute__((ext_vector_type(4)));
typedef _Float16 f16x8 __attribute__((ext_vector_type(8)));

#define T_STEPS 4096
#define BATCH   16
#define IN      64
#define HID     256
#define G4      1024

// dynamic LDS layout (bytes)
#define WT_BYTES   131072              // 8 chunk-slots * 1024 thr * 16 B
#define HB_OFF     131072              // 2 * 256 f16 = 1024 B
#define ESH_OFF    132096              // 256 f32 = 1024 B
#define XSF_OFF    133120              // 64 f32 = 256 B
#define SMEM_BYTES 133376

__device__ __forceinline__ float fdot2(f16x2 a, f16x2 b, float c) {
#if __has_builtin(__builtin_amdgcn_fdot2)
    return __builtin_amdgcn_fdot2(a, b, c, false);
#else
    return c + (float)a.x * (float)b.x + (float)a.y * (float)b.y;
#endif
}

__device__ __forceinline__ float sigf(float x) {
    return 1.0f / (1.0f + __expf(-x));
}
__device__ __forceinline__ float tanh_fast(float x) {
    return 2.0f * sigf(2.0f * x) - 1.0f;
}

// ---------------- Kernel A: x_gates precompute (transposed store) ----------
__global__ __launch_bounds__(256) void xg_precompute(
    const float* __restrict__ x, const float* __restrict__ W_ih,
    const float* __restrict__ b_ih, const float* __restrict__ b_hh,
    _Float16* __restrict__ xg)
{
    const int b   = blockIdx.x;
    const int t0  = blockIdx.y * 128;
    const int tid = threadIdx.x;

    __shared__ __align__(16) f16x2 xs2[IN / 2];

    f16x2 wih[4][32];
    float bias[4];
    const float2* W2 = (const float2*)W_ih;
    #pragma unroll
    for (int g = 0; g < 4; ++g) {
        const int r = tid + g * 256;
        #pragma unroll
        for (int m = 0; m < 32; ++m) {
            float2 v = W2[r * 32 + m];
            wih[g][m] = f16x2{(_Float16)v.x, (_Float16)v.y};
        }
        bias[g] = b_ih[r] + b_hh[r];
    }

    for (int tt = 0; tt < 128; ++tt) {
        const int t = t0 + tt;
        if (tid < 32) {
            float2 v = ((const float2*)x)[(t * BATCH + b) * 32 + tid];
            xs2[tid] = f16x2{(_Float16)v.x, (_Float16)v.y};
        }
        __syncthreads();
        float acc[4] = {bias[0], bias[1], bias[2], bias[3]};
        #pragma unroll
        for (int m = 0; m < 32; ++m) {
            f16x2 xv = xs2[m];
            #pragma unroll
            for (int g = 0; g < 4; ++g) acc[g] = fdot2(wih[g][m], xv, acc[g]);
        }
        // transposed: [t][b][unit*4 + gate], one b64 per unit
        f16x4 v4 = f16x4{(_Float16)acc[0], (_Float16)acc[1],
                         (_Float16)acc[2], (_Float16)acc[3]};
        ((f16x4*)xg)[(t * BATCH + b) * 256 + tid] = v4;
        __syncthreads();
    }
}

// ---------------- Kernel B: persistent recurrence ----------------
template <bool PRE>
__global__ __launch_bounds__(1024, 4) void lstm_rec(
    const float* __restrict__ x,     const float* __restrict__ W_ih,
    const float* __restrict__ W_hh,  const float* __restrict__ b_ih,
    const float* __restrict__ b_hh,  const float* __restrict__ W_lin,
    const float* __restrict__ b_lin, const float* __restrict__ h0,
    const float* __restrict__ c0,    const _Float16* __restrict__ xg,
    float* __restrict__ out)
{
    const int b   = blockIdx.x;
    const int tid = threadIdx.x;
    const int j   = tid >> 2;   // hidden unit 0..255
    const int q   = tid & 3;    // k-quarter: h[64q .. 64q+64)

    extern __shared__ __align__(16) char smem[];
    f16x8*    wt8  = (f16x8*)smem;                    // [8][1024]
    _Float16* hbuf = (_Float16*)(smem + HB_OFF);      // [2][256]
    float*    esh  = (float*)(smem + ESH_OFF);        // [256]
    float*    xsf  = (float*)(smem + XSF_OFF);        // [64]

    // ---- one-time: W_hh -> fp16 regs (4 rows x 24 pairs) + LDS tail ----
    // Row r=j+256g, quarter float4 range [r*64 + 16q, +16): 12 f4 -> regs,
    // 4 f4 -> 2 LDS chunks.
    f16x2 wr[4][24];
    const float4* Wh4 = (const float4*)W_hh;          // row stride 64 float4
    #pragma unroll
    for (int g = 0; g < 4; ++g) {
        const int base = (j + 256 * g) * 64 + q * 16;
        #pragma unroll
        for (int c = 0; c < 6; ++c) {
            float4 a = Wh4[base + 2 * c];
            float4 d = Wh4[base + 2 * c + 1];
            wr[g][c * 4 + 0] = f16x2{(_Float16)a.x, (_Float16)a.y};
            wr[g][c * 4 + 1] = f16x2{(_Float16)a.z, (_Float16)a.w};
            wr[g][c * 4 + 2] = f16x2{(_Float16)d.x, (_Float16)d.y};
            wr[g][c * 4 + 3] = f16x2{(_Float16)d.z, (_Float16)d.w};
        }
        #pragma unroll
        for (int c = 0; c < 2; ++c) {
            union { f16x8 v; f16x2 p[4]; } u;
            float4 a = Wh4[base + 12 + 2 * c];
            float4 d = Wh4[base + 13 + 2 * c];
            u.p[0] = f16x2{(_Float16)a.x, (_Float16)a.y};
            u.p[1] = f16x2{(_Float16)a.z, (_Float16)a.w};
            u.p[2] = f16x2{(_Float16)d.x, (_Float16)d.y};
            u.p[3] = f16x2{(_Float16)d.z, (_Float16)d.w};
            wt8[(g * 2 + c) * 1024 + tid] = u.v;
        }
    }

    float bias[4] = {0.f, 0.f, 0.f, 0.f};
    if (!PRE && q == 0) {
        #pragma unroll
        for (int g = 0; g < 4; ++g)
            bias[g] = b_ih[j + g * 256] + b_hh[j + g * 256];
    }

    // ---- state (q==0 lanes own unit j) ----
    float cst = 0.f, hval = 0.f;
    if (q == 0) {
        cst  = c0[b * HID + j];
        hval = h0[b * HID + j];
        hbuf[j] = (_Float16)hval;   // buffer 0
    }

    f16x4 xgc = f16x4{0, 0, 0, 0};
    float xnext = 0.0f;
    if (PRE) {
        if (q == 0) xgc = ((const f16x4*)xg)[b * 256 + j];
    } else {
        if (tid < IN) xnext = x[b * IN + tid];
    }

    for (int t = 0; t < T_STEPS; ++t) {
        __syncthreads();  // h(t) in hbuf[t&1] visible
        const f16x8* hb = (const f16x8*)(hbuf + (t & 1) * 256);

        f16x4 xgn = f16x4{0, 0, 0, 0};
        if (PRE) {
            if (q == 0 && t + 1 < T_STEPS)
                xgn = ((const f16x4*)xg)[((t + 1) * BATCH + b) * 256 + j];
        }

        float acc[4] = {0.f, 0.f, 0.f, 0.f};

        if (!PRE) {
            if (tid < IN) xsf[tid] = xnext;
            __syncthreads();
            if (tid < IN && t + 1 < T_STEPS)
                xnext = x[((t + 1) * BATCH + b) * IN + tid];
            const float4* W4 = (const float4*)W_ih;   // row stride 16 float4
            #pragma unroll
            for (int g = 0; g < 4; ++g) {
                const int r = j + g * 256;
                #pragma unroll
                for (int ic = 0; ic < 4; ++ic) {
                    float4 wv = W4[r * 16 + q * 4 + ic];
                    const int k = q * 16 + ic * 4;
                    acc[g] += wv.x * xsf[k] + wv.y * xsf[k + 1]
                            + wv.z * xsf[k + 2] + wv.w * xsf[k + 3];
                }
            }
        }

        // ---- h-quarter . W_hh rows: 6 reg chunks + 2 LDS chunks ----
        #pragma unroll
        for (int c = 0; c < 6; ++c) {
            union { f16x8 v; f16x2 p[4]; } hu;
            hu.v = hb[q * 8 + c];
            #pragma unroll
            for (int u = 0; u < 4; ++u) {
                #pragma unroll
                for (int g = 0; g < 4; ++g)
                    acc[g] = fdot2(wr[g][c * 4 + u], hu.p[u], acc[g]);
            }
        }
        #pragma unroll
        for (int c = 0; c < 2; ++c) {
            union { f16x8 v; f16x2 p[4]; } hu, wu[4];
            hu.v = hb[q * 8 + 6 + c];
            #pragma unroll
            for (int g = 0; g < 4; ++g) wu[g].v = wt8[(g * 2 + c) * 1024 + tid];
            #pragma unroll
            for (int u = 0; u < 4; ++u) {
                #pragma unroll
                for (int g = 0; g < 4; ++g)
                    acc[g] = fdot2(wu[g].p[u], hu.p[u], acc[g]);
            }
        }

        // ---- combine k-quarters within the quad (DPP) ----
        #pragma unroll
        for (int g = 0; g < 4; ++g) {
            acc[g] += __shfl_xor(acc[g], 1, 64);
            acc[g] += __shfl_xor(acc[g], 2, 64);
        }

        // ---- gates: q==0 lane has complete i,f,g,o for unit j ----
        if (q == 0) {
            float p0, p1, p2, p3;
            if (PRE) {
                p0 = acc[0] + (float)xgc[0];
                p1 = acc[1] + (float)xgc[1];
                p2 = acc[2] + (float)xgc[2];
                p3 = acc[3] + (float)xgc[3];
            } else {
                p0 = acc[0] + bias[0];
                p1 = acc[1] + bias[1];
                p2 = acc[2] + bias[2];
                p3 = acc[3] + bias[3];
            }
            float gi = sigf(p0);
            float gf = sigf(p1);
            float gg = tanh_fast(p2);
            float go = sigf(p3);
            cst  = gf * cst + gi * gg;
            hval = go * tanh_fast(cst);
            hbuf[((t + 1) & 1) * 256 + j] = (_Float16)hval;
            xgc = xgn;
        }
    }

    // ---- epilogue: y[b] = sigmoid(h . W_lin + b_lin) ----
    if (q == 0) esh[j] = hval * W_lin[j];
    __syncthreads();
    if (tid == 0) {
        float z = b_lin[0];
        for (int n = 0; n < 256; ++n) z += esh[n];
        out[b] = sigf(z);
    }
}

extern "C" void kernel_launch(void* const* d_in, const int* in_sizes, int n_in,
                              void* d_out, int out_size, void* d_ws, size_t ws_size,
                              hipStream_t stream) {
    const float* x     = (const float*)d_in[0];
    const float* W_ih  = (const float*)d_in[1];
    const float* W_hh  = (const float*)d_in[2];
    const float* b_ih  = (const float*)d_in[3];
    const float* b_hh  = (const float*)d_in[4];
    const float* W_lin = (const float*)d_in[5];
    const float* b_lin = (const float*)d_in[6];
    const float* h0    = (const float*)d_in[7];
    const float* c0    = (const float*)d_in[8];
    float* out = (float*)d_out;

    const size_t need = (size_t)T_STEPS * BATCH * G4 * sizeof(_Float16); // 128 MB
    if (ws_size >= need) {
        _Float16* xg = (_Float16*)d_ws;
        (void)hipFuncSetAttribute((const void*)lstm_rec<true>,
                                  hipFuncAttributeMaxDynamicSharedMemorySize,
                                  SMEM_BYTES);
        xg_precompute<<<dim3(BATCH, 32), 256, 0, stream>>>(x, W_ih, b_ih, b_hh, xg);
        lstm_rec<true><<<dim3(BATCH), 1024, SMEM_BYTES, stream>>>(
            x, W_ih, W_hh, b_ih, b_hh, W_lin, b_lin, h0, c0, xg, out);
    } else {
        (void)hipFuncSetAttribute((const void*)lstm_rec<false>,
                                  hipFuncAttributeMaxDynamicSharedMemorySize,
                                  SMEM_BYTES);
        lstm_rec<false><<<dim3(BATCH), 1024, SMEM_BYTES, stream>>>(
            x, W_ih, W_hh, b_ih, b_hh, W_lin, b_lin, h0, c0,
            (const _Float16*)nullptr, out);
    }
}

// Round 6
// 6504.519 us; speedup vs baseline: 1.8628x; 1.4347x over previous
//
#include <hip/hip_runtime.h>
#include <hip/hip_bf16.h>

// LSTM T=4096, B=16, I=64, H=256 (4H=1024 gate rows), O=1.
//
// R6: 16 WGs x 768 threads (12 waves -> 3 waves/SIMD, 168-reg cap).
// Thread = (unit j = tid&255, k-third s = tid>>8), k in [88s, 88s+88),
// K padded 256->264 (pad weights zeroed so pad h can be anything).
//  - s is WAVE-UNIFORM: h-chunk reads are LDS broadcasts (R5's q=tid&3 gave
//    4-way bank conflicts: 128-B spacing = exact bank wrap; 3.36e7 conflicts).
//  - weights: 8 chunks/row x 4 rows = 128 f16x2 in VGPRs + 3 chunks/row in
//    LDS (144 KB). 128 + ~27 working = 155 <= 168 cap (R5: 136 > 128 ->
//    total spill collapse, VGPR_Count=64).
//  - k-reduce: s=1,2 write acc[4] as float4 psum; s=0 combines after B2.
//  - xg precomputed transposed [t][b][unit*4+gate] fp16; s=0 prefetches b64.

typedef _Float16 f16x2 __attribute__((ext_vector_type(2)));
typedef _Float16 f16x4 __attribute__((ext_vector_type(4)));
typedef _Float16 f16x8 __attribute__((ext_vector_type(8)));

#define T_STEPS 4096
#define BATCH   16
#define IN      64
#define HID     256
#define G4      1024
#define NTHR    768
#define KC      11        // chunks per row per thread (8 reg + 3 LDS)
#define REGC    8
#define LDSC    3
#define HPAD    264       // padded K (33 f16x8 chunks)

// dynamic LDS layout (bytes)
#define WT_OFF   0                        // 12*768*16 = 147456
#define HB_OFF   147456                   // 2*264*2   = 1056
#define PS_OFF   148512                   // 2*256*16  = 8192
#define ESH_OFF  156704                   // 256*4     = 1024
#define SMEM_BYTES 157728

__device__ __forceinline__ float fdot2(f16x2 a, f16x2 b, float c) {
#if __has_builtin(__builtin_amdgcn_fdot2)
    return __builtin_amdgcn_fdot2(a, b, c, false);
#else
    return c + (float)a.x * (float)b.x + (float)a.y * (float)b.y;
#endif
}

__device__ __forceinline__ float sigf(float x) {
    return 1.0f / (1.0f + __expf(-x));
}
__device__ __forceinline__ float tanh_fast(float x) {
    return 2.0f * sigf(2.0f * x) - 1.0f;
}

// ---------------- Kernel A: x_gates precompute (transposed store) ----------
__global__ __launch_bounds__(256) void xg_precompute(
    const float* __restrict__ x, const float* __restrict__ W_ih,
    const float* __restrict__ b_ih, const float* __restrict__ b_hh,
    _Float16* __restrict__ xg)
{
    const int b   = blockIdx.x;
    const int t0  = blockIdx.y * 128;
    const int tid = threadIdx.x;

    __shared__ __align__(16) f16x2 xs2[IN / 2];

    f16x2 wih[4][32];
    float bias[4];
    const float2* W2 = (const float2*)W_ih;
    #pragma unroll
    for (int g = 0; g < 4; ++g) {
        const int r = tid + g * 256;
        #pragma unroll
        for (int m = 0; m < 32; ++m) {
            float2 v = W2[r * 32 + m];
            wih[g][m] = f16x2{(_Float16)v.x, (_Float16)v.y};
        }
        bias[g] = b_ih[r] + b_hh[r];
    }

    for (int tt = 0; tt < 128; ++tt) {
        const int t = t0 + tt;
        if (tid < 32) {
            float2 v = ((const float2*)x)[(t * BATCH + b) * 32 + tid];
            xs2[tid] = f16x2{(_Float16)v.x, (_Float16)v.y};
        }
        __syncthreads();
        float acc[4] = {bias[0], bias[1], bias[2], bias[3]};
        #pragma unroll
        for (int m = 0; m < 32; ++m) {
            f16x2 xv = xs2[m];
            #pragma unroll
            for (int g = 0; g < 4; ++g) acc[g] = fdot2(wih[g][m], xv, acc[g]);
        }
        f16x4 v4 = f16x4{(_Float16)acc[0], (_Float16)acc[1],
                         (_Float16)acc[2], (_Float16)acc[3]};
        ((f16x4*)xg)[(t * BATCH + b) * 256 + tid] = v4;
        __syncthreads();
    }
}

// ---------------- Kernel B: persistent recurrence ----------------
template <bool PRE>
__global__ __launch_bounds__(NTHR, 3) void lstm_rec(
    const float* __restrict__ x,     const float* __restrict__ W_ih,
    const float* __restrict__ W_hh,  const float* __restrict__ b_ih,
    const float* __restrict__ b_hh,  const float* __restrict__ W_lin,
    const float* __restrict__ b_lin, const float* __restrict__ h0,
    const float* __restrict__ c0,    const _Float16* __restrict__ xg,
    float* __restrict__ out)
{
    const int b   = blockIdx.x;
    const int tid = threadIdx.x;
    const int j   = tid & 255;   // hidden unit
    const int s   = tid >> 8;    // k-third 0..2 (wave-uniform)

    extern __shared__ __align__(16) char smem[];
    f16x8*    wt8  = (f16x8*)(smem + WT_OFF);     // [12][768]
    _Float16* hbuf = (_Float16*)(smem + HB_OFF);  // [2][264]
    float4*   psum = (float4*)(smem + PS_OFF);    // [2][256]
    float*    esh  = (float*)(smem + ESH_OFF);    // [256]

    // ---- one-time: W_hh -> fp16 regs + LDS tail ----
    // Row r=j+256g; chunk c covers k = 88s + 8c .. +8. Reg chunks c=0..7
    // (k<=239, always real). LDS chunks c=8..10; s==2,c==10 -> k0=256: pad 0.
    f16x2 wr[128];                                // [g][c][pair]
    const float4* Wh4 = (const float4*)W_hh;      // row stride 64 float4
    #pragma unroll
    for (int g = 0; g < 4; ++g) {
        const int r = j + 256 * g;
        #pragma unroll
        for (int c = 0; c < REGC; ++c) {
            const int f4i = r * 64 + (88 * s + 8 * c) / 4;
            float4 a = Wh4[f4i];
            float4 d = Wh4[f4i + 1];
            wr[g * 32 + c * 4 + 0] = f16x2{(_Float16)a.x, (_Float16)a.y};
            wr[g * 32 + c * 4 + 1] = f16x2{(_Float16)a.z, (_Float16)a.w};
            wr[g * 32 + c * 4 + 2] = f16x2{(_Float16)d.x, (_Float16)d.y};
            wr[g * 32 + c * 4 + 3] = f16x2{(_Float16)d.z, (_Float16)d.w};
        }
        #pragma unroll
        for (int c = 0; c < LDSC; ++c) {
            const int k0 = 88 * s + 8 * (REGC + c);
            union { f16x8 v; f16x2 p[4]; } u;
            if (k0 < 256) {
                float4 a = Wh4[r * 64 + k0 / 4];
                float4 d = Wh4[r * 64 + k0 / 4 + 1];
                u.p[0] = f16x2{(_Float16)a.x, (_Float16)a.y};
                u.p[1] = f16x2{(_Float16)a.z, (_Float16)a.w};
                u.p[2] = f16x2{(_Float16)d.x, (_Float16)d.y};
                u.p[3] = f16x2{(_Float16)d.z, (_Float16)d.w};
            } else {
                u.p[0] = f16x2{0, 0}; u.p[1] = f16x2{0, 0};
                u.p[2] = f16x2{0, 0}; u.p[3] = f16x2{0, 0};
            }
            wt8[(g * LDSC + c) * NTHR + tid] = u.v;
        }
    }

    float bias[4] = {0.f, 0.f, 0.f, 0.f};
    if (!PRE && s == 0) {
        #pragma unroll
        for (int g = 0; g < 4; ++g)
            bias[g] = b_ih[j + g * 256] + b_hh[j + g * 256];
    }

    // ---- state ----
    float cst = 0.f, hval = 0.f;
    if (s == 0) {
        cst  = c0[b * HID + j];
        hval = h0[b * HID + j];
        hbuf[j] = (_Float16)hval;                  // buffer 0
    }
    if (tid < 8) {                                 // zero K-pad in both buffers
        hbuf[256 + tid]        = (_Float16)0.f;
        hbuf[HPAD + 256 + tid] = (_Float16)0.f;
    }

    union XU { uint2 u; f16x4 h; };
    XU xc; xc.u = uint2{0, 0};
    if (PRE && s == 0) xc.u = ((const uint2*)xg)[b * 256 + j];

    for (int t = 0; t < T_STEPS; ++t) {
        __syncthreads();  // B1: h(t) + (first iter) weights visible
        const f16x8* hb = (const f16x8*)(hbuf + (t & 1) * HPAD);

        XU xn; xn.u = uint2{0, 0};
        if (PRE && s == 0 && t + 1 < T_STEPS)
            xn.u = ((const uint2*)xg)[((t + 1) * BATCH + b) * 256 + j];

        float acc[4] = {0.f, 0.f, 0.f, 0.f};

        if (!PRE && s != 0) {   // fallback: x-projection split over s=1,2
            const float4* Wi4 = (const float4*)W_ih;       // row stride 16
            const float4* xv4 = (const float4*)(x + ((size_t)t * BATCH + b) * IN)
                                + (s - 1) * 8;
            #pragma unroll
            for (int q = 0; q < 8; ++q) {
                float4 xv = xv4[q];
                #pragma unroll
                for (int g = 0; g < 4; ++g) {
                    float4 w = Wi4[(j + 256 * g) * 16 + (s - 1) * 8 + q];
                    acc[g] += w.x * xv.x + w.y * xv.y + w.z * xv.z + w.w * xv.w;
                }
            }
        }

        // ---- 8 register chunks ----
        #pragma unroll
        for (int c = 0; c < REGC; ++c) {
            union { f16x8 v; f16x2 p[4]; } hu;
            hu.v = hb[s * KC + c];
            #pragma unroll
            for (int u = 0; u < 4; ++u) {
                #pragma unroll
                for (int g = 0; g < 4; ++g)
                    acc[g] = fdot2(wr[g * 32 + c * 4 + u], hu.p[u], acc[g]);
            }
        }
        // ---- 3 LDS chunks (one weight union live at a time) ----
        #pragma unroll
        for (int c = 0; c < LDSC; ++c) {
            union { f16x8 v; f16x2 p[4]; } hu;
            hu.v = hb[s * KC + REGC + c];
            #pragma unroll
            for (int g = 0; g < 4; ++g) {
                union { f16x8 v; f16x2 p[4]; } wu;
                wu.v = wt8[(g * LDSC + c) * NTHR + tid];
                #pragma unroll
                for (int u = 0; u < 4; ++u)
                    acc[g] = fdot2(wu.p[u], hu.p[u], acc[g]);
            }
        }

        if (s != 0)
            psum[(s - 1) * 256 + j] = float4{acc[0], acc[1], acc[2], acc[3]};
        __syncthreads();  // B2: psums ready

        if (s == 0) {
            float4 p1 = psum[j];
            float4 p2 = psum[256 + j];
            float e0, e1, e2, e3;
            if (PRE) {
                e0 = (float)xc.h[0]; e1 = (float)xc.h[1];
                e2 = (float)xc.h[2]; e3 = (float)xc.h[3];
            } else {
                e0 = bias[0]; e1 = bias[1]; e2 = bias[2]; e3 = bias[3];
            }
            float gi = sigf(acc[0] + p1.x + p2.x + e0);
            float gf = sigf(acc[1] + p1.y + p2.y + e1);
            float gg = tanh_fast(acc[2] + p1.z + p2.z + e2);
            float go = sigf(acc[3] + p1.w + p2.w + e3);
            cst  = gf * cst + gi * gg;
            hval = go * tanh_fast(cst);
            hbuf[((t + 1) & 1) * HPAD + j] = (_Float16)hval;  // h(t+1)
            xc = xn;
        }
    }

    // ---- epilogue: y[b] = sigmoid(h . W_lin + b_lin) ----
    if (s == 0) esh[j] = hval * W_lin[j];
    __syncthreads();
    if (tid == 0) {
        float z = b_lin[0];
        for (int n = 0; n < 256; ++n) z += esh[n];
        out[b] = sigf(z);
    }
}

extern "C" void kernel_launch(void* const* d_in, const int* in_sizes, int n_in,
                              void* d_out, int out_size, void* d_ws, size_t ws_size,
                              hipStream_t stream) {
    const float* x     = (const float*)d_in[0];
    const float* W_ih  = (const float*)d_in[1];
    const float* W_hh  = (const float*)d_in[2];
    const float* b_ih  = (const float*)d_in[3];
    const float* b_hh  = (const float*)d_in[4];
    const float* W_lin = (const float*)d_in[5];
    const float* b_lin = (const float*)d_in[6];
    const float* h0    = (const float*)d_in[7];
    const float* c0    = (const float*)d_in[8];
    float* out = (float*)d_out;

    const size_t need = (size_t)T_STEPS * BATCH * G4 * sizeof(_Float16); // 128 MB
    if (ws_size >= need) {
        _Float16* xg = (_Float16*)d_ws;
        (void)hipFuncSetAttribute((const void*)lstm_rec<true>,
                                  hipFuncAttributeMaxDynamicSharedMemorySize,
                                  SMEM_BYTES);
        xg_precompute<<<dim3(BATCH, 32), 256, 0, stream>>>(x, W_ih, b_ih, b_hh, xg);
        lstm_rec<true><<<dim3(BATCH), NTHR, SMEM_BYTES, stream>>>(
            x, W_ih, W_hh, b_ih, b_hh, W_lin, b_lin, h0, c0, xg, out);
    } else {
        (void)hipFuncSetAttribute((const void*)lstm_rec<false>,
                                  hipFuncAttributeMaxDynamicSharedMemorySize,
                                  SMEM_BYTES);
        lstm_rec<false><<<dim3(BATCH), NTHR, SMEM_BYTES, stream>>>(
            x, W_ih, W_hh, b_ih, b_hh, W_lin, b_lin, h0, c0,
            (const _Float16*)nullptr, out);
    }
}

// Round 8
// 5196.370 us; speedup vs baseline: 2.3318x; 1.2517x over previous
//
#include <hip/hip_runtime.h>
#include <hip/hip_bf16.h>

// LSTM T=4096, B=16, I=64, H=256 (4H=1024 gate rows), O=1.
//
// R8 = R7 with the compile fix: cvt_pk_fp8_f32's word-select must be an
// immediate -> template<bool WORD>. Design unchanged:
// fp8 MFMA persistent kernel. 16 WGs (1 batch each) x 1024 thr (16 waves,
// 4 waves/SIMD, 128-reg tier).
//  - W_hh as e4m3 B-fragments in registers: wave w owns stripes
//    {w,16+w,32+w,48+w} = gate rows i/f/g/o for units 16w..16w+15.
//    64 VGPRs of weights; MFMA reads VGPR/AGPR directly -> allocator-proof.
//  - h as 256 e4m3 bytes in LDS, swizzled addr(k)=((k>>3)&3)*64+(k>>5)*8+(k&7)
//    -> each lane's A fragment is 64 contiguous bytes: 4 ds_read_b128.
//  - All 16 A rows carry the same h => D rows identical => acc reg0 of any
//    lane = preact(col). i,f,g,o for unit w*16+col land in the SAME lane.
//  - ONE barrier/step; x@W_ih precomputed fp16 transposed in d_ws.

typedef _Float16 f16x2 __attribute__((ext_vector_type(2)));
typedef _Float16 f16x4 __attribute__((ext_vector_type(4)));
typedef float    f32x4 __attribute__((ext_vector_type(4)));

#define T_STEPS 4096
#define BATCH   16
#define IN      64
#define HID     256
#define G4      1024

__device__ __forceinline__ float fdot2(f16x2 a, f16x2 b, float c) {
#if __has_builtin(__builtin_amdgcn_fdot2)
    return __builtin_amdgcn_fdot2(a, b, c, false);
#else
    return c + (float)a.x * (float)b.x + (float)a.y * (float)b.y;
#endif
}

__device__ __forceinline__ float sigf(float x) {
    return 1.0f / (1.0f + __expf(-x));
}
__device__ __forceinline__ float tanh_fast(float x) {
    return 2.0f * sigf(2.0f * x) - 1.0f;
}

template <bool WORD>
__device__ __forceinline__ int pk_fp8(float lo, float hi, int old) {
    return __builtin_amdgcn_cvt_pk_fp8_f32(lo, hi, old, WORD);
}

// ---------------- Kernel A: x_gates precompute (transposed store) ----------
__global__ __launch_bounds__(256) void xg_precompute(
    const float* __restrict__ x, const float* __restrict__ W_ih,
    const float* __restrict__ b_ih, const float* __restrict__ b_hh,
    _Float16* __restrict__ xg)
{
    const int b   = blockIdx.x;
    const int t0  = blockIdx.y * 128;
    const int tid = threadIdx.x;

    __shared__ __align__(16) f16x2 xs2[IN / 2];

    f16x2 wih[4][32];
    float bias[4];
    const float2* W2 = (const float2*)W_ih;
    #pragma unroll
    for (int g = 0; g < 4; ++g) {
        const int r = tid + g * 256;
        #pragma unroll
        for (int m = 0; m < 32; ++m) {
            float2 v = W2[r * 32 + m];
            wih[g][m] = f16x2{(_Float16)v.x, (_Float16)v.y};
        }
        bias[g] = b_ih[r] + b_hh[r];
    }

    for (int tt = 0; tt < 128; ++tt) {
        const int t = t0 + tt;
        if (tid < 32) {
            float2 v = ((const float2*)x)[(t * BATCH + b) * 32 + tid];
            xs2[tid] = f16x2{(_Float16)v.x, (_Float16)v.y};
        }
        __syncthreads();
        float acc[4] = {bias[0], bias[1], bias[2], bias[3]};
        #pragma unroll
        for (int m = 0; m < 32; ++m) {
            f16x2 xv = xs2[m];
            #pragma unroll
            for (int g = 0; g < 4; ++g) acc[g] = fdot2(wih[g][m], xv, acc[g]);
        }
        f16x4 v4 = f16x4{(_Float16)acc[0], (_Float16)acc[1],
                         (_Float16)acc[2], (_Float16)acc[3]};
        ((f16x4*)xg)[(t * BATCH + b) * 256 + tid] = v4;
        __syncthreads();
    }
}

// ---------------- Kernel B: MFMA persistent recurrence ----------------
__global__ __launch_bounds__(1024, 4) void lstm_mfma(
    const float* __restrict__ W_hh,  const float* __restrict__ W_lin,
    const float* __restrict__ b_lin, const float* __restrict__ h0,
    const float* __restrict__ c0,    const _Float16* __restrict__ xg,
    float* __restrict__ out)
{
    const int b   = blockIdx.x;
    const int tid = threadIdx.x;
    const int w   = tid >> 6;     // wave 0..15
    const int l   = tid & 63;     // lane
    const int col = l & 15;       // MFMA col for this lane
    const int g4  = l >> 4;       // k-group 0..3

    __shared__ __align__(16) unsigned char hs[2][256];  // h e4m3, A-swizzled
    __shared__ float esh[256];

    const int u  = w * 16 + col;                        // unit this lane covers
    const int su = ((u >> 3) & 3) * 64 + (u >> 5) * 8 + (u & 7);  // swz(u)

    // ---- one-time: W_hh -> e4m3 B-fragments in registers ----
    unsigned long long wf[4][8];
    {
        const float4* Wh4 = (const float4*)W_hh;        // row stride 64
        #pragma unroll
        for (int t4 = 0; t4 < 4; ++t4) {
            const int row = t4 * 256 + w * 16 + col;
            #pragma unroll
            for (int c = 0; c < 8; ++c) {
                const int k0 = c * 32 + g4 * 8;
                float4 v0 = Wh4[row * 64 + k0 / 4];
                float4 v1 = Wh4[row * 64 + k0 / 4 + 1];
                int lo = pk_fp8<false>(v0.x, v0.y, 0);
                lo     = pk_fp8<true >(v0.z, v0.w, lo);
                int hi = pk_fp8<false>(v1.x, v1.y, 0);
                hi     = pk_fp8<true >(v1.z, v1.w, hi);
                wf[t4][c] = ((unsigned long long)(unsigned int)hi << 32)
                          |  (unsigned long long)(unsigned int)lo;
            }
        }
    }

    // ---- state (redundant across the 4 lane-groups; write by l<16) ----
    float cst  = c0[b * HID + u];
    float hval = h0[b * HID + u];
    if (l < 16) {
        int p = pk_fp8<false>(hval, hval, 0);
        hs[0][su] = (unsigned char)(p & 0xff);
    }

    union XU { uint2 i; f16x4 h; };
    XU xc; xc.i = ((const uint2*)xg)[b * 256 + u];

    for (int t = 0; t < T_STEPS; ++t) {
        __syncthreads();   // h(t) in hs[t&1] visible

        // A-fragments: 4 x b128; read r holds chunks 2r (dw x,y), 2r+1 (z,w)
        const uint4* hsv = (const uint4*)(&hs[t & 1][0]);
        uint4 ar0 = hsv[g4 * 4 + 0];
        uint4 ar1 = hsv[g4 * 4 + 1];
        uint4 ar2 = hsv[g4 * 4 + 2];
        uint4 ar3 = hsv[g4 * 4 + 3];

        // prefetch next step's x-gates
        const int tn = (t + 1 < T_STEPS) ? (t + 1) : t;
        XU xn; xn.i = ((const uint2*)xg)[(tn * BATCH + b) * 256 + u];

        f32x4 acc0 = {0.f, 0.f, 0.f, 0.f};
        f32x4 acc1 = {0.f, 0.f, 0.f, 0.f};
        f32x4 acc2 = {0.f, 0.f, 0.f, 0.f};
        f32x4 acc3 = {0.f, 0.f, 0.f, 0.f};

        #pragma unroll
        for (int c = 0; c < 8; ++c) {
            unsigned int d0, d1;
            switch (c) {
                case 0: d0 = ar0.x; d1 = ar0.y; break;
                case 1: d0 = ar0.z; d1 = ar0.w; break;
                case 2: d0 = ar1.x; d1 = ar1.y; break;
                case 3: d0 = ar1.z; d1 = ar1.w; break;
                case 4: d0 = ar2.x; d1 = ar2.y; break;
                case 5: d0 = ar2.z; d1 = ar2.w; break;
                case 6: d0 = ar3.x; d1 = ar3.y; break;
                default: d0 = ar3.z; d1 = ar3.w; break;
            }
            const long A = (long)(((unsigned long long)d1 << 32) | d0);
            acc0 = __builtin_amdgcn_mfma_f32_16x16x32_fp8_fp8(A, (long)wf[0][c], acc0, 0, 0, 0);
            acc1 = __builtin_amdgcn_mfma_f32_16x16x32_fp8_fp8(A, (long)wf[1][c], acc1, 0, 0, 0);
            acc2 = __builtin_amdgcn_mfma_f32_16x16x32_fp8_fp8(A, (long)wf[2][c], acc2, 0, 0, 0);
            acc3 = __builtin_amdgcn_mfma_f32_16x16x32_fp8_fp8(A, (long)wf[3][c], acc3, 0, 0, 0);
        }

        // D rows identical -> reg0 of ANY lane = preact(col). Epilogue on all
        // 64 lanes (4x redundant), write guarded to l<16.
        float gi = sigf(acc0[0] + (float)xc.h[0]);
        float gf = sigf(acc1[0] + (float)xc.h[1]);
        float gg = tanh_fast(acc2[0] + (float)xc.h[2]);
        float go = sigf(acc3[0] + (float)xc.h[3]);
        cst  = gf * cst + gi * gg;
        hval = go * tanh_fast(cst);
        if (l < 16) {
            int p = pk_fp8<false>(hval, hval, 0);
            hs[(t + 1) & 1][su] = (unsigned char)(p & 0xff);
        }
        xc = xn;
    }

    // ---- epilogue: y[b] = sigmoid(h . W_lin + b_lin) ----
    if (l < 16) esh[u] = hval * W_lin[u];
    __syncthreads();
    if (tid == 0) {
        float z = b_lin[0];
        for (int n = 0; n < 256; ++n) z += esh[n];
        out[b] = sigf(z);
    }
}

// ---------------- Fallback (ws too small): R6 dot2 kernel, x streamed ------
#define NTHR 768
#define KC   11
#define REGC 8
#define LDSC 3
#define HPAD 264
#define WT_OFF   0
#define HB_OFF   147456
#define PS_OFF   148512
#define ESH_OFF  156704
#define SMEM_BYTES 157728
typedef _Float16 f16x8 __attribute__((ext_vector_type(8)));

__global__ __launch_bounds__(NTHR, 3) void lstm_fb(
    const float* __restrict__ x,     const float* __restrict__ W_ih,
    const float* __restrict__ W_hh,  const float* __restrict__ b_ih,
    const float* __restrict__ b_hh,  const float* __restrict__ W_lin,
    const float* __restrict__ b_lin, const float* __restrict__ h0,
    const float* __restrict__ c0,    float* __restrict__ out)
{
    const int b   = blockIdx.x;
    const int tid = threadIdx.x;
    const int j   = tid & 255;
    const int s   = tid >> 8;

    extern __shared__ __align__(16) char smem[];
    f16x8*    wt8  = (f16x8*)(smem + WT_OFF);
    _Float16* hbuf = (_Float16*)(smem + HB_OFF);
    float4*   psum = (float4*)(smem + PS_OFF);
    float*    esh  = (float*)(smem + ESH_OFF);

    f16x2 wr[128];
    const float4* Wh4 = (const float4*)W_hh;
    #pragma unroll
    for (int g = 0; g < 4; ++g) {
        const int r = j + 256 * g;
        #pragma unroll
        for (int c = 0; c < REGC; ++c) {
            const int f4i = r * 64 + (88 * s + 8 * c) / 4;
            float4 a = Wh4[f4i];
            float4 d = Wh4[f4i + 1];
            wr[g * 32 + c * 4 + 0] = f16x2{(_Float16)a.x, (_Float16)a.y};
            wr[g * 32 + c * 4 + 1] = f16x2{(_Float16)a.z, (_Float16)a.w};
            wr[g * 32 + c * 4 + 2] = f16x2{(_Float16)d.x, (_Float16)d.y};
            wr[g * 32 + c * 4 + 3] = f16x2{(_Float16)d.z, (_Float16)d.w};
        }
        #pragma unroll
        for (int c = 0; c < LDSC; ++c) {
            const int k0 = 88 * s + 8 * (REGC + c);
            union { f16x8 v; f16x2 p[4]; } u;
            if (k0 < 256) {
                float4 a = Wh4[r * 64 + k0 / 4];
                float4 d = Wh4[r * 64 + k0 / 4 + 1];
                u.p[0] = f16x2{(_Float16)a.x, (_Float16)a.y};
                u.p[1] = f16x2{(_Float16)a.z, (_Float16)a.w};
                u.p[2] = f16x2{(_Float16)d.x, (_Float16)d.y};
                u.p[3] = f16x2{(_Float16)d.z, (_Float16)d.w};
            } else {
                u.p[0] = f16x2{0, 0}; u.p[1] = f16x2{0, 0};
                u.p[2] = f16x2{0, 0}; u.p[3] = f16x2{0, 0};
            }
            wt8[(g * LDSC + c) * NTHR + tid] = u.v;
        }
    }

    float bias[4] = {0.f, 0.f, 0.f, 0.f};
    if (s == 0) {
        #pragma unroll
        for (int g = 0; g < 4; ++g)
            bias[g] = b_ih[j + g * 256] + b_hh[j + g * 256];
    }

    float cst = 0.f, hval = 0.f;
    if (s == 0) {
        cst  = c0[b * HID + j];
        hval = h0[b * HID + j];
        hbuf[j] = (_Float16)hval;
    }
    if (tid < 8) {
        hbuf[256 + tid]        = (_Float16)0.f;
        hbuf[HPAD + 256 + tid] = (_Float16)0.f;
    }

    for (int t = 0; t < T_STEPS; ++t) {
        __syncthreads();
        const f16x8* hb = (const f16x8*)(hbuf + (t & 1) * HPAD);

        float acc[4] = {0.f, 0.f, 0.f, 0.f};
        if (s != 0) {
            const float4* Wi4 = (const float4*)W_ih;
            const float4* xv4 = (const float4*)(x + ((size_t)t * BATCH + b) * IN)
                                + (s - 1) * 8;
            #pragma unroll
            for (int q = 0; q < 8; ++q) {
                float4 xv = xv4[q];
                #pragma unroll
                for (int g = 0; g < 4; ++g) {
                    float4 wv = Wi4[(j + 256 * g) * 16 + (s - 1) * 8 + q];
                    acc[g] += wv.x * xv.x + wv.y * xv.y + wv.z * xv.z + wv.w * xv.w;
                }
            }
        }
        #pragma unroll
        for (int c = 0; c < REGC; ++c) {
            union { f16x8 v; f16x2 p[4]; } hu;
            hu.v = hb[s * KC + c];
            #pragma unroll
            for (int uu = 0; uu < 4; ++uu) {
                #pragma unroll
                for (int g = 0; g < 4; ++g)
                    acc[g] = fdot2(wr[g * 32 + c * 4 + uu], hu.p[uu], acc[g]);
            }
        }
        #pragma unroll
        for (int c = 0; c < LDSC; ++c) {
            union { f16x8 v; f16x2 p[4]; } hu;
            hu.v = hb[s * KC + REGC + c];
            #pragma unroll
            for (int g = 0; g < 4; ++g) {
                union { f16x8 v; f16x2 p[4]; } wu;
                wu.v = wt8[(g * LDSC + c) * NTHR + tid];
                #pragma unroll
                for (int uu = 0; uu < 4; ++uu)
                    acc[g] = fdot2(wu.p[uu], hu.p[uu], acc[g]);
            }
        }
        if (s != 0)
            psum[(s - 1) * 256 + j] = float4{acc[0], acc[1], acc[2], acc[3]};
        __syncthreads();
        if (s == 0) {
            float4 p1 = psum[j];
            float4 p2 = psum[256 + j];
            float gi = sigf(acc[0] + p1.x + p2.x + bias[0]);
            float gf = sigf(acc[1] + p1.y + p2.y + bias[1]);
            float gg = tanh_fast(acc[2] + p1.z + p2.z + bias[2]);
            float go = sigf(acc[3] + p1.w + p2.w + bias[3]);
            cst  = gf * cst + gi * gg;
            hval = go * tanh_fast(cst);
            hbuf[((t + 1) & 1) * HPAD + j] = (_Float16)hval;
        }
    }

    if (s == 0) esh[j] = hval * W_lin[j];
    __syncthreads();
    if (tid == 0) {
        float z = b_lin[0];
        for (int n = 0; n < 256; ++n) z += esh[n];
        out[b] = sigf(z);
    }
}

extern "C" void kernel_launch(void* const* d_in, const int* in_sizes, int n_in,
                              void* d_out, int out_size, void* d_ws, size_t ws_size,
                              hipStream_t stream) {
    const float* x     = (const float*)d_in[0];
    const float* W_ih  = (const float*)d_in[1];
    const float* W_hh  = (const float*)d_in[2];
    const float* b_ih  = (const float*)d_in[3];
    const float* b_hh  = (const float*)d_in[4];
    const float* W_lin = (const float*)d_in[5];
    const float* b_lin = (const float*)d_in[6];
    const float* h0    = (const float*)d_in[7];
    const float* c0    = (const float*)d_in[8];
    float* out = (float*)d_out;

    const size_t need = (size_t)T_STEPS * BATCH * G4 * sizeof(_Float16); // 128 MB
    if (ws_size >= need) {
        _Float16* xg = (_Float16*)d_ws;
        xg_precompute<<<dim3(BATCH, 32), 256, 0, stream>>>(x, W_ih, b_ih, b_hh, xg);
        lstm_mfma<<<dim3(BATCH), 1024, 0, stream>>>(
            W_hh, W_lin, b_lin, h0, c0, xg, out);
    } else {
        (void)hipFuncSetAttribute((const void*)lstm_fb,
                                  hipFuncAttributeMaxDynamicSharedMemorySize,
                                  SMEM_BYTES);
        lstm_fb<<<dim3(BATCH), NTHR, SMEM_BYTES, stream>>>(
            x, W_ih, W_hh, b_ih, b_hh, W_lin, b_lin, h0, c0, out);
    }
}

// Round 10
// 4442.488 us; speedup vs baseline: 2.7274x; 1.1697x over previous
//
#include <hip/hip_runtime.h>
#include <hip/hip_bf16.h>

// LSTM T=4096, B=16, I=64, H=256 (4H=1024 gate rows), O=1.
//
// R10: int8 MFMA (16x16x64) persistent kernel. 16 WGs x 1024 thr (16 waves,
// 4 waves/SIMD). Structure = R8 (verified) with the fp8 K=32 MFMA replaced by
// i8 K=64:
//  - 16 MFMA/wave/step (vs R8's 32) -> per-CU floor ~1306 cyc (R8: 2483).
//  - int8 per-row symmetric quant: preact = (rowmax/127^2)*acc_int + xg.
//    Exactly factorizable; int32 accumulate exact; ~8x less noise than fp8
//    (R9's MX path failed at 1.56e-2 absmax from internal block reduction).
//  - wave w, lane col=l&15 owns unit u=w*16+col; gate rows g*256+u for
//    g=0..3. Weights: 4 gates x 4 chunks x i32x4 = 64 VGPRs (MFMA operands,
//    allocator-proof). rowmax via 2x shfl_xor across g4 groups (init only).
//  - h as int8 in LDS, k-map k=64c+16*g4+j is the IDENTITY layout (no
//    swizzle): lane reads hsv[4c+g4], 4x b128 broadcast, conflict-free.
//    A and B packed with the same (lane,reg,byte)->k map: any HW-map
//    deviation is a shared k-permutation and cancels in the dot product.
//  - All 16 A rows carry the same h => D rows identical => acc[0] of any
//    lane = preact(col); i,f,g,o in the SAME lane; ONE barrier/step.
//  - x@W_ih precomputed fp16 transposed [t][b][unit*4+gate] in d_ws.

typedef _Float16 f16x2 __attribute__((ext_vector_type(2)));
typedef _Float16 f16x4 __attribute__((ext_vector_type(4)));
typedef int      i32x4 __attribute__((ext_vector_type(4)));

#define T_STEPS 4096
#define BATCH   16
#define IN      64
#define HID     256
#define G4      1024

__device__ __forceinline__ float fdot2(f16x2 a, f16x2 b, float c) {
#if __has_builtin(__builtin_amdgcn_fdot2)
    return __builtin_amdgcn_fdot2(a, b, c, false);
#else
    return c + (float)a.x * (float)b.x + (float)a.y * (float)b.y;
#endif
}

__device__ __forceinline__ float sigf(float x) {
    return 1.0f / (1.0f + __expf(-x));
}
__device__ __forceinline__ float tanh_fast(float x) {
    return 2.0f * sigf(2.0f * x) - 1.0f;
}

// ---------------- Kernel A: x_gates precompute (transposed store) ----------
__global__ __launch_bounds__(256) void xg_precompute(
    const float* __restrict__ x, const float* __restrict__ W_ih,
    const float* __restrict__ b_ih, const float* __restrict__ b_hh,
    _Float16* __restrict__ xg)
{
    const int b   = blockIdx.x;
    const int t0  = blockIdx.y * 128;
    const int tid = threadIdx.x;

    __shared__ __align__(16) f16x2 xs2[IN / 2];

    f16x2 wih[4][32];
    float bias[4];
    const float2* W2 = (const float2*)W_ih;
    #pragma unroll
    for (int g = 0; g < 4; ++g) {
        const int r = tid + g * 256;
        #pragma unroll
        for (int m = 0; m < 32; ++m) {
            float2 v = W2[r * 32 + m];
            wih[g][m] = f16x2{(_Float16)v.x, (_Float16)v.y};
        }
        bias[g] = b_ih[r] + b_hh[r];
    }

    for (int tt = 0; tt < 128; ++tt) {
        const int t = t0 + tt;
        if (tid < 32) {
            float2 v = ((const float2*)x)[(t * BATCH + b) * 32 + tid];
            xs2[tid] = f16x2{(_Float16)v.x, (_Float16)v.y};
        }
        __syncthreads();
        float acc[4] = {bias[0], bias[1], bias[2], bias[3]};
        #pragma unroll
        for (int m = 0; m < 32; ++m) {
            f16x2 xv = xs2[m];
            #pragma unroll
            for (int g = 0; g < 4; ++g) acc[g] = fdot2(wih[g][m], xv, acc[g]);
        }
        f16x4 v4 = f16x4{(_Float16)acc[0], (_Float16)acc[1],
                         (_Float16)acc[2], (_Float16)acc[3]};
        ((f16x4*)xg)[(t * BATCH + b) * 256 + tid] = v4;
        __syncthreads();
    }
}

// ---------------- Kernel B: i8-MFMA persistent recurrence ----------------
__global__ __launch_bounds__(1024, 4) void lstm_mfma(
    const float* __restrict__ W_hh,  const float* __restrict__ W_lin,
    const float* __restrict__ b_lin, const float* __restrict__ h0,
    const float* __restrict__ c0,    const _Float16* __restrict__ xg,
    float* __restrict__ out)
{
    const int b   = blockIdx.x;
    const int tid = threadIdx.x;
    const int w   = tid >> 6;     // wave 0..15
    const int l   = tid & 63;     // lane
    const int col = l & 15;       // MFMA col for this lane
    const int g4  = l >> 4;       // k lane-group 0..3

    __shared__ __align__(16) signed char hs[2][256];  // h int8, identity layout
    __shared__ float esh[256];

    const int u = w * 16 + col;   // unit this lane covers

    // ---- one-time: per-gate-row max, then W_hh -> int8 B-fragments ----
    // Lane slice per gate row (row = g*256 + u): k in {64c+16*g4 .. +16},
    // c = 0..3. float4 index = 16c + 4*g4 + d.
    const float4* Wh4 = (const float4*)W_hh;          // row stride 64 float4
    float qs[4], ksc[4];
    {
        float rm[4];
        #pragma unroll
        for (int g = 0; g < 4; ++g) {
            const int row = g * 256 + u;
            float m = 0.0f;
            #pragma unroll
            for (int c = 0; c < 4; ++c) {
                #pragma unroll
                for (int d = 0; d < 4; ++d) {
                    float4 v = Wh4[row * 64 + 16 * c + 4 * g4 + d];
                    m = fmaxf(m, fmaxf(fmaxf(fabsf(v.x), fabsf(v.y)),
                                       fmaxf(fabsf(v.z), fabsf(v.w))));
                }
            }
            rm[g] = m;
        }
        #pragma unroll
        for (int g = 0; g < 4; ++g) {                  // max across g4 groups
            rm[g] = fmaxf(rm[g], __shfl_xor(rm[g], 16, 64));
            rm[g] = fmaxf(rm[g], __shfl_xor(rm[g], 32, 64));
            rm[g] = fmaxf(rm[g], 1e-20f);
            qs[g]  = 127.0f / rm[g];
            ksc[g] = rm[g] * (1.0f / 16129.0f);        // rm/127^2
        }
    }
    i32x4 wf[4][4];
    #pragma unroll
    for (int g = 0; g < 4; ++g) {
        const int row = g * 256 + u;
        #pragma unroll
        for (int c = 0; c < 4; ++c) {
            union { int i[4]; i32x4 v; } uu;
            #pragma unroll
            for (int d = 0; d < 4; ++d) {
                float4 v = Wh4[row * 64 + 16 * c + 4 * g4 + d];
                int b0 = (int)rintf(v.x * qs[g]) & 255;
                int b1 = (int)rintf(v.y * qs[g]) & 255;
                int b2 = (int)rintf(v.z * qs[g]) & 255;
                int b3 = (int)rintf(v.w * qs[g]) & 255;
                uu.i[d] = b0 | (b1 << 8) | (b2 << 16) | (b3 << 24);
            }
            wf[g][c] = uu.v;
        }
    }

    // ---- state (lane l<16 owns unit u's write) ----
    float cst  = c0[b * HID + u];
    float hval = h0[b * HID + u];
    if (l < 16)
        hs[0][u] = (signed char)(int)rintf(hval * 127.0f);

    union XU { uint2 i; f16x4 h; };
    XU xc; xc.i = ((const uint2*)xg)[b * 256 + u];

    for (int t = 0; t < T_STEPS; ++t) {
        __syncthreads();   // h(t) in hs[t&1] visible

        // A fragments: chunk c = bytes [64c + 16*g4, +16) -> 4x b128 broadcast
        const uint4* hsv = (const uint4*)(&hs[t & 1][0]);
        union AU { uint4 q; i32x4 v; } a0, a1, a2, a3;
        a0.q = hsv[g4];
        a1.q = hsv[4 + g4];
        a2.q = hsv[8 + g4];
        a3.q = hsv[12 + g4];

        // prefetch next step's x-gates
        const int tn = (t + 1 < T_STEPS) ? (t + 1) : t;
        XU xn; xn.i = ((const uint2*)xg)[(tn * BATCH + b) * 256 + u];

        i32x4 acc0 = {0, 0, 0, 0};
        i32x4 acc1 = {0, 0, 0, 0};
        i32x4 acc2 = {0, 0, 0, 0};
        i32x4 acc3 = {0, 0, 0, 0};

        acc0 = __builtin_amdgcn_mfma_i32_16x16x64_i8(a0.v, wf[0][0], acc0, 0, 0, 0);
        acc1 = __builtin_amdgcn_mfma_i32_16x16x64_i8(a0.v, wf[1][0], acc1, 0, 0, 0);
        acc2 = __builtin_amdgcn_mfma_i32_16x16x64_i8(a0.v, wf[2][0], acc2, 0, 0, 0);
        acc3 = __builtin_amdgcn_mfma_i32_16x16x64_i8(a0.v, wf[3][0], acc3, 0, 0, 0);
        acc0 = __builtin_amdgcn_mfma_i32_16x16x64_i8(a1.v, wf[0][1], acc0, 0, 0, 0);
        acc1 = __builtin_amdgcn_mfma_i32_16x16x64_i8(a1.v, wf[1][1], acc1, 0, 0, 0);
        acc2 = __builtin_amdgcn_mfma_i32_16x16x64_i8(a1.v, wf[2][1], acc2, 0, 0, 0);
        acc3 = __builtin_amdgcn_mfma_i32_16x16x64_i8(a1.v, wf[3][1], acc3, 0, 0, 0);
        acc0 = __builtin_amdgcn_mfma_i32_16x16x64_i8(a2.v, wf[0][2], acc0, 0, 0, 0);
        acc1 = __builtin_amdgcn_mfma_i32_16x16x64_i8(a2.v, wf[1][2], acc1, 0, 0, 0);
        acc2 = __builtin_amdgcn_mfma_i32_16x16x64_i8(a2.v, wf[2][2], acc2, 0, 0, 0);
        acc3 = __builtin_amdgcn_mfma_i32_16x16x64_i8(a2.v, wf[3][2], acc3, 0, 0, 0);
        acc0 = __builtin_amdgcn_mfma_i32_16x16x64_i8(a3.v, wf[0][3], acc0, 0, 0, 0);
        acc1 = __builtin_amdgcn_mfma_i32_16x16x64_i8(a3.v, wf[1][3], acc1, 0, 0, 0);
        acc2 = __builtin_amdgcn_mfma_i32_16x16x64_i8(a3.v, wf[2][3], acc2, 0, 0, 0);
        acc3 = __builtin_amdgcn_mfma_i32_16x16x64_i8(a3.v, wf[3][3], acc3, 0, 0, 0);

        // D rows identical -> acc reg0 of ANY lane = int preact(col).
        float gi = sigf((float)acc0[0] * ksc[0] + (float)xc.h[0]);
        float gf = sigf((float)acc1[0] * ksc[1] + (float)xc.h[1]);
        float gg = tanh_fast((float)acc2[0] * ksc[2] + (float)xc.h[2]);
        float go = sigf((float)acc3[0] * ksc[3] + (float)xc.h[3]);
        cst  = gf * cst + gi * gg;
        hval = go * tanh_fast(cst);
        if (l < 16)
            hs[(t + 1) & 1][u] = (signed char)(int)rintf(hval * 127.0f);
        xc = xn;
    }

    // ---- epilogue: y[b] = sigmoid(h . W_lin + b_lin) ----
    if (l < 16) esh[u] = hval * W_lin[u];
    __syncthreads();
    if (tid == 0) {
        float z = b_lin[0];
        for (int n = 0; n < 256; ++n) z += esh[n];
        out[b] = sigf(z);
    }
}

// ---------------- Fallback (ws too small): R6 dot2 kernel, x streamed ------
#define NTHR 768
#define KC   11
#define REGC 8
#define LDSC 3
#define HPAD 264
#define WT_OFF   0
#define HB_OFF   147456
#define PS_OFF   148512
#define ESH_OFF  156704
#define SMEM_BYTES 157728
typedef _Float16 f16x8 __attribute__((ext_vector_type(8)));

__global__ __launch_bounds__(NTHR, 3) void lstm_fb(
    const float* __restrict__ x,     const float* __restrict__ W_ih,
    const float* __restrict__ W_hh,  const float* __restrict__ b_ih,
    const float* __restrict__ b_hh,  const float* __restrict__ W_lin,
    const float* __restrict__ b_lin, const float* __restrict__ h0,
    const float* __restrict__ c0,    float* __restrict__ out)
{
    const int b   = blockIdx.x;
    const int tid = threadIdx.x;
    const int j   = tid & 255;
    const int s   = tid >> 8;

    extern __shared__ __align__(16) char smem[];
    f16x8*    wt8  = (f16x8*)(smem + WT_OFF);
    _Float16* hbuf = (_Float16*)(smem + HB_OFF);
    float4*   psum = (float4*)(smem + PS_OFF);
    float*    esh  = (float*)(smem + ESH_OFF);

    f16x2 wr[128];
    const float4* Wh4 = (const float4*)W_hh;
    #pragma unroll
    for (int g = 0; g < 4; ++g) {
        const int r = j + 256 * g;
        #pragma unroll
        for (int c = 0; c < REGC; ++c) {
            const int f4i = r * 64 + (88 * s + 8 * c) / 4;
            float4 a = Wh4[f4i];
            float4 d = Wh4[f4i + 1];
            wr[g * 32 + c * 4 + 0] = f16x2{(_Float16)a.x, (_Float16)a.y};
            wr[g * 32 + c * 4 + 1] = f16x2{(_Float16)a.z, (_Float16)a.w};
            wr[g * 32 + c * 4 + 2] = f16x2{(_Float16)d.x, (_Float16)d.y};
            wr[g * 32 + c * 4 + 3] = f16x2{(_Float16)d.z, (_Float16)d.w};
        }
        #pragma unroll
        for (int c = 0; c < LDSC; ++c) {
            const int k0 = 88 * s + 8 * (REGC + c);
            union { f16x8 v; f16x2 p[4]; } u;
            if (k0 < 256) {
                float4 a = Wh4[r * 64 + k0 / 4];
                float4 d = Wh4[r * 64 + k0 / 4 + 1];
                u.p[0] = f16x2{(_Float16)a.x, (_Float16)a.y};
                u.p[1] = f16x2{(_Float16)a.z, (_Float16)a.w};
                u.p[2] = f16x2{(_Float16)d.x, (_Float16)d.y};
                u.p[3] = f16x2{(_Float16)d.z, (_Float16)d.w};
            } else {
                u.p[0] = f16x2{0, 0}; u.p[1] = f16x2{0, 0};
                u.p[2] = f16x2{0, 0}; u.p[3] = f16x2{0, 0};
            }
            wt8[(g * LDSC + c) * NTHR + tid] = u.v;
        }
    }

    float bias[4] = {0.f, 0.f, 0.f, 0.f};
    if (s == 0) {
        #pragma unroll
        for (int g = 0; g < 4; ++g)
            bias[g] = b_ih[j + g * 256] + b_hh[j + g * 256];
    }

    float cst = 0.f, hval = 0.f;
    if (s == 0) {
        cst  = c0[b * HID + j];
        hval = h0[b * HID + j];
        hbuf[j] = (_Float16)hval;
    }
    if (tid < 8) {
        hbuf[256 + tid]        = (_Float16)0.f;
        hbuf[HPAD + 256 + tid] = (_Float16)0.f;
    }

    for (int t = 0; t < T_STEPS; ++t) {
        __syncthreads();
        const f16x8* hb = (const f16x8*)(hbuf + (t & 1) * HPAD);

        float acc[4] = {0.f, 0.f, 0.f, 0.f};
        if (s != 0) {
            const float4* Wi4 = (const float4*)W_ih;
            const float4* xv4 = (const float4*)(x + ((size_t)t * BATCH + b) * IN)
                                + (s - 1) * 8;
            #pragma unroll
            for (int q = 0; q < 8; ++q) {
                float4 xv = xv4[q];
                #pragma unroll
                for (int g = 0; g < 4; ++g) {
                    float4 wv = Wi4[(j + 256 * g) * 16 + (s - 1) * 8 + q];
                    acc[g] += wv.x * xv.x + wv.y * xv.y + wv.z * xv.z + wv.w * xv.w;
                }
            }
        }
        #pragma unroll
        for (int c = 0; c < REGC; ++c) {
            union { f16x8 v; f16x2 p[4]; } hu;
            hu.v = hb[s * KC + c];
            #pragma unroll
            for (int uu = 0; uu < 4; ++uu) {
                #pragma unroll
                for (int g = 0; g < 4; ++g)
                    acc[g] = fdot2(wr[g * 32 + c * 4 + uu], hu.p[uu], acc[g]);
            }
        }
        #pragma unroll
        for (int c = 0; c < LDSC; ++c) {
            union { f16x8 v; f16x2 p[4]; } hu;
            hu.v = hb[s * KC + REGC + c];
            #pragma unroll
            for (int g = 0; g < 4; ++g) {
                union { f16x8 v; f16x2 p[4]; } wu;
                wu.v = wt8[(g * LDSC + c) * NTHR + tid];
                #pragma unroll
                for (int uu = 0; uu < 4; ++uu)
                    acc[g] = fdot2(wu.p[uu], hu.p[uu], acc[g]);
            }
        }
        if (s != 0)
            psum[(s - 1) * 256 + j] = float4{acc[0], acc[1], acc[2], acc[3]};
        __syncthreads();
        if (s == 0) {
            float4 p1 = psum[j];
            float4 p2 = psum[256 + j];
            float gi = sigf(acc[0] + p1.x + p2.x + bias[0]);
            float gf = sigf(acc[1] + p1.y + p2.y + bias[1]);
            float gg = tanh_fast(acc[2] + p1.z + p2.z + bias[2]);
            float go = sigf(acc[3] + p1.w + p2.w + bias[3]);
            cst  = gf * cst + gi * gg;
            hval = go * tanh_fast(cst);
            hbuf[((t + 1) & 1) * HPAD + j] = (_Float16)hval;
        }
    }

    if (s == 0) esh[j] = hval * W_lin[j];
    __syncthreads();
    if (tid == 0) {
        float z = b_lin[0];
        for (int n = 0; n < 256; ++n) z += esh[n];
        out[b] = sigf(z);
    }
}

extern "C" void kernel_launch(void* const* d_in, const int* in_sizes, int n_in,
                              void* d_out, int out_size, void* d_ws, size_t ws_size,
                              hipStream_t stream) {
    const float* x     = (const float*)d_in[0];
    const float* W_ih  = (const float*)d_in[1];
    const float* W_hh  = (const float*)d_in[2];
    const float* b_ih  = (const float*)d_in[3];
    const float* b_hh  = (const float*)d_in[4];
    const float* W_lin = (const float*)d_in[5];
    const float* b_lin = (const float*)d_in[6];
    const float* h0    = (const float*)d_in[7];
    const float* c0    = (const float*)d_in[8];
    float* out = (float*)d_out;

    const size_t need = (size_t)T_STEPS * BATCH * G4 * sizeof(_Float16); // 128 MB
    if (ws_size >= need) {
        _Float16* xg = (_Float16*)d_ws;
        xg_precompute<<<dim3(BATCH, 32), 256, 0, stream>>>(x, W_ih, b_ih, b_hh, xg);
        lstm_mfma<<<dim3(BATCH), 1024, 0, stream>>>(
            W_hh, W_lin, b_lin, h0, c0, xg, out);
    } else {
        (void)hipFuncSetAttribute((const void*)lstm_fb,
                                  hipFuncAttributeMaxDynamicSharedMemorySize,
                                  SMEM_BYTES);
        lstm_fb<<<dim3(BATCH), NTHR, SMEM_BYTES, stream>>>(
            x, W_ih, W_hh, b_ih, b_hh, W_lin, b_lin, h0, c0, out);
    }
}

// Round 11
// 3188.946 us; speedup vs baseline: 3.7996x; 1.3931x over previous
//
#include <hip/hip_runtime.h>
#include <hip/hip_bf16.h>

// LSTM T=4096, B=16, I=64, H=256 (4H=1024 gate rows), O=1.
//
// R11 = R10 (i8 K=64 MFMA persistent kernel, verified 4259us / absmax 2e-3)
// with the VALU fix: R10's counters showed per-active-CU VALUBusy 78% vs
// MfmaUtil 41% -- the IEEE division inside sigf (no fast-math at -O3) costs
// ~10 inst x 5 activations/thread/step. Replace with v_rcp_f32
// (__builtin_amdgcn_rcpf, ~1ulp; noise 1e-7 << int8 budget 2e-3).
// Also: incremental xg pointer (kills a per-step integer mul).
//
// Structure (unchanged, verified):
//  - 16 WGs x 1024 thr (16 waves, 4/SIMD). Wave w, lane col=l&15 owns unit
//    u=w*16+col; gate rows g*256+u. Weights: 4x4 i32x4 = 64 VGPRs of MFMA
//    operands (allocator-proof). Per-gate-row symmetric int8 quant,
//    preact = (rowmax/127^2)*acc_int + xg; int32 accumulate exact.
//  - h int8 in LDS, identity k-map, 4x b128 broadcast reads, 0 conflicts.
//  - 16 MFMA/wave/step; ONE barrier/step; all-lane epilogue (4x lane-
//    redundant, issue-free), h write by l<16.
//  - x@W_ih precomputed fp16 transposed [t][b][unit*4+gate] in d_ws.

typedef _Float16 f16x2 __attribute__((ext_vector_type(2)));
typedef _Float16 f16x4 __attribute__((ext_vector_type(4)));
typedef int      i32x4 __attribute__((ext_vector_type(4)));

#define T_STEPS 4096
#define BATCH   16
#define IN      64
#define HID     256
#define G4      1024

__device__ __forceinline__ float fdot2(f16x2 a, f16x2 b, float c) {
#if __has_builtin(__builtin_amdgcn_fdot2)
    return __builtin_amdgcn_fdot2(a, b, c, false);
#else
    return c + (float)a.x * (float)b.x + (float)a.y * (float)b.y;
#endif
}

__device__ __forceinline__ float fast_rcp(float x) {
#if __has_builtin(__builtin_amdgcn_rcpf)
    return __builtin_amdgcn_rcpf(x);
#else
    return 1.0f / x;
#endif
}

__device__ __forceinline__ float sigf(float x) {
    return fast_rcp(1.0f + __expf(-x));      // v_mul, v_exp, v_add, v_rcp
}
__device__ __forceinline__ float tanh_fast(float x) {
    return 2.0f * sigf(2.0f * x) - 1.0f;
}

// ---------------- Kernel A: x_gates precompute (transposed store) ----------
__global__ __launch_bounds__(256) void xg_precompute(
    const float* __restrict__ x, const float* __restrict__ W_ih,
    const float* __restrict__ b_ih, const float* __restrict__ b_hh,
    _Float16* __restrict__ xg)
{
    const int b   = blockIdx.x;
    const int t0  = blockIdx.y * 128;
    const int tid = threadIdx.x;

    __shared__ __align__(16) f16x2 xs2[IN / 2];

    f16x2 wih[4][32];
    float bias[4];
    const float2* W2 = (const float2*)W_ih;
    #pragma unroll
    for (int g = 0; g < 4; ++g) {
        const int r = tid + g * 256;
        #pragma unroll
        for (int m = 0; m < 32; ++m) {
            float2 v = W2[r * 32 + m];
            wih[g][m] = f16x2{(_Float16)v.x, (_Float16)v.y};
        }
        bias[g] = b_ih[r] + b_hh[r];
    }

    for (int tt = 0; tt < 128; ++tt) {
        const int t = t0 + tt;
        if (tid < 32) {
            float2 v = ((const float2*)x)[(t * BATCH + b) * 32 + tid];
            xs2[tid] = f16x2{(_Float16)v.x, (_Float16)v.y};
        }
        __syncthreads();
        float acc[4] = {bias[0], bias[1], bias[2], bias[3]};
        #pragma unroll
        for (int m = 0; m < 32; ++m) {
            f16x2 xv = xs2[m];
            #pragma unroll
            for (int g = 0; g < 4; ++g) acc[g] = fdot2(wih[g][m], xv, acc[g]);
        }
        f16x4 v4 = f16x4{(_Float16)acc[0], (_Float16)acc[1],
                         (_Float16)acc[2], (_Float16)acc[3]};
        ((f16x4*)xg)[(t * BATCH + b) * 256 + tid] = v4;
        __syncthreads();
    }
}

// ---------------- Kernel B: i8-MFMA persistent recurrence ----------------
__global__ __launch_bounds__(1024, 4) void lstm_mfma(
    const float* __restrict__ W_hh,  const float* __restrict__ W_lin,
    const float* __restrict__ b_lin, const float* __restrict__ h0,
    const float* __restrict__ c0,    const _Float16* __restrict__ xg,
    float* __restrict__ out)
{
    const int b   = blockIdx.x;
    const int tid = threadIdx.x;
    const int w   = tid >> 6;     // wave 0..15
    const int l   = tid & 63;     // lane
    const int col = l & 15;       // MFMA col for this lane
    const int g4  = l >> 4;       // k lane-group 0..3

    __shared__ __align__(16) signed char hs[2][256];  // h int8, identity layout
    __shared__ float esh[256];

    const int u = w * 16 + col;   // unit this lane covers

    // ---- one-time: per-gate-row max, then W_hh -> int8 B-fragments ----
    const float4* Wh4 = (const float4*)W_hh;          // row stride 64 float4
    float qs[4], ksc[4];
    {
        float rm[4];
        #pragma unroll
        for (int g = 0; g < 4; ++g) {
            const int row = g * 256 + u;
            float m = 0.0f;
            #pragma unroll
            for (int c = 0; c < 4; ++c) {
                #pragma unroll
                for (int d = 0; d < 4; ++d) {
                    float4 v = Wh4[row * 64 + 16 * c + 4 * g4 + d];
                    m = fmaxf(m, fmaxf(fmaxf(fabsf(v.x), fabsf(v.y)),
                                       fmaxf(fabsf(v.z), fabsf(v.w))));
                }
            }
            rm[g] = m;
        }
        #pragma unroll
        for (int g = 0; g < 4; ++g) {                  // max across g4 groups
            rm[g] = fmaxf(rm[g], __shfl_xor(rm[g], 16, 64));
            rm[g] = fmaxf(rm[g], __shfl_xor(rm[g], 32, 64));
            rm[g] = fmaxf(rm[g], 1e-20f);
            qs[g]  = 127.0f / rm[g];
            ksc[g] = rm[g] * (1.0f / 16129.0f);        // rm/127^2
        }
    }
    i32x4 wf[4][4];
    #pragma unroll
    for (int g = 0; g < 4; ++g) {
        const int row = g * 256 + u;
        #pragma unroll
        for (int c = 0; c < 4; ++c) {
            union { int i[4]; i32x4 v; } uu;
            #pragma unroll
            for (int d = 0; d < 4; ++d) {
                float4 v = Wh4[row * 64 + 16 * c + 4 * g4 + d];
                int b0 = (int)rintf(v.x * qs[g]) & 255;
                int b1 = (int)rintf(v.y * qs[g]) & 255;
                int b2 = (int)rintf(v.z * qs[g]) & 255;
                int b3 = (int)rintf(v.w * qs[g]) & 255;
                uu.i[d] = b0 | (b1 << 8) | (b2 << 16) | (b3 << 24);
            }
            wf[g][c] = uu.v;
        }
    }

    // ---- state (lane l<16 owns unit u's write) ----
    float cst  = c0[b * HID + u];
    float hval = h0[b * HID + u];
    if (l < 16)
        hs[0][u] = (signed char)(int)rintf(hval * 127.0f);

    union XU { uint2 i; f16x4 h; };
    const uint2* xp = (const uint2*)xg + b * 256 + u;  // stride BATCH*256/step
    XU xc; xc.i = *xp;
    xp += BATCH * 256;

    for (int t = 0; t < T_STEPS; ++t) {
        __syncthreads();   // h(t) in hs[t&1] visible

        // A fragments: chunk c = bytes [64c + 16*g4, +16) -> 4x b128 broadcast
        const uint4* hsv = (const uint4*)(&hs[t & 1][0]);
        union AU { uint4 q; i32x4 v; } a0, a1, a2, a3;
        a0.q = hsv[g4];
        a1.q = hsv[4 + g4];
        a2.q = hsv[8 + g4];
        a3.q = hsv[12 + g4];

        // prefetch next step's x-gates (pointer-incremented)
        XU xn;
        if (t + 1 < T_STEPS) { xn.i = *xp; xp += BATCH * 256; }
        else                 { xn = xc; }

        i32x4 acc0 = {0, 0, 0, 0};
        i32x4 acc1 = {0, 0, 0, 0};
        i32x4 acc2 = {0, 0, 0, 0};
        i32x4 acc3 = {0, 0, 0, 0};

        acc0 = __builtin_amdgcn_mfma_i32_16x16x64_i8(a0.v, wf[0][0], acc0, 0, 0, 0);
        acc1 = __builtin_amdgcn_mfma_i32_16x16x64_i8(a0.v, wf[1][0], acc1, 0, 0, 0);
        acc2 = __builtin_amdgcn_mfma_i32_16x16x64_i8(a0.v, wf[2][0], acc2, 0, 0, 0);
        acc3 = __builtin_amdgcn_mfma_i32_16x16x64_i8(a0.v, wf[3][0], acc3, 0, 0, 0);
        acc0 = __builtin_amdgcn_mfma_i32_16x16x64_i8(a1.v, wf[0][1], acc0, 0, 0, 0);
        acc1 = __builtin_amdgcn_mfma_i32_16x16x64_i8(a1.v, wf[1][1], acc1, 0, 0, 0);
        acc2 = __builtin_amdgcn_mfma_i32_16x16x64_i8(a1.v, wf[2][1], acc2, 0, 0, 0);
        acc3 = __builtin_amdgcn_mfma_i32_16x16x64_i8(a1.v, wf[3][1], acc3, 0, 0, 0);
        acc0 = __builtin_amdgcn_mfma_i32_16x16x64_i8(a2.v, wf[0][2], acc0, 0, 0, 0);
        acc1 = __builtin_amdgcn_mfma_i32_16x16x64_i8(a2.v, wf[1][2], acc1, 0, 0, 0);
        acc2 = __builtin_amdgcn_mfma_i32_16x16x64_i8(a2.v, wf[2][2], acc2, 0, 0, 0);
        acc3 = __builtin_amdgcn_mfma_i32_16x16x64_i8(a2.v, wf[3][2], acc3, 0, 0, 0);
        acc0 = __builtin_amdgcn_mfma_i32_16x16x64_i8(a3.v, wf[0][3], acc0, 0, 0, 0);
        acc1 = __builtin_amdgcn_mfma_i32_16x16x64_i8(a3.v, wf[1][3], acc1, 0, 0, 0);
        acc2 = __builtin_amdgcn_mfma_i32_16x16x64_i8(a3.v, wf[2][3], acc2, 0, 0, 0);
        acc3 = __builtin_amdgcn_mfma_i32_16x16x64_i8(a3.v, wf[3][3], acc3, 0, 0, 0);

        // D rows identical -> acc reg0 of ANY lane = int preact(col).
        float gi = sigf((float)acc0[0] * ksc[0] + (float)xc.h[0]);
        float gf = sigf((float)acc1[0] * ksc[1] + (float)xc.h[1]);
        float gg = tanh_fast((float)acc2[0] * ksc[2] + (float)xc.h[2]);
        float go = sigf((float)acc3[0] * ksc[3] + (float)xc.h[3]);
        cst  = gf * cst + gi * gg;
        hval = go * tanh_fast(cst);
        if (l < 16)
            hs[(t + 1) & 1][u] = (signed char)(int)rintf(hval * 127.0f);
        xc = xn;
    }

    // ---- epilogue: y[b] = sigmoid(h . W_lin + b_lin) ----
    if (l < 16) esh[u] = hval * W_lin[u];
    __syncthreads();
    if (tid == 0) {
        float z = b_lin[0];
        for (int n = 0; n < 256; ++n) z += esh[n];
        out[b] = sigf(z);
    }
}

// ---------------- Fallback (ws too small): R6 dot2 kernel, x streamed ------
#define NTHR 768
#define KC   11
#define REGC 8
#define LDSC 3
#define HPAD 264
#define WT_OFF   0
#define HB_OFF   147456
#define PS_OFF   148512
#define ESH_OFF  156704
#define SMEM_BYTES 157728
typedef _Float16 f16x8 __attribute__((ext_vector_type(8)));

__global__ __launch_bounds__(NTHR, 3) void lstm_fb(
    const float* __restrict__ x,     const float* __restrict__ W_ih,
    const float* __restrict__ W_hh,  const float* __restrict__ b_ih,
    const float* __restrict__ b_hh,  const float* __restrict__ W_lin,
    const float* __restrict__ b_lin, const float* __restrict__ h0,
    const float* __restrict__ c0,    float* __restrict__ out)
{
    const int b   = blockIdx.x;
    const int tid = threadIdx.x;
    const int j   = tid & 255;
    const int s   = tid >> 8;

    extern __shared__ __align__(16) char smem[];
    f16x8*    wt8  = (f16x8*)(smem + WT_OFF);
    _Float16* hbuf = (_Float16*)(smem + HB_OFF);
    float4*   psum = (float4*)(smem + PS_OFF);
    float*    esh  = (float*)(smem + ESH_OFF);

    f16x2 wr[128];
    const float4* Wh4 = (const float4*)W_hh;
    #pragma unroll
    for (int g = 0; g < 4; ++g) {
        const int r = j + 256 * g;
        #pragma unroll
        for (int c = 0; c < REGC; ++c) {
            const int f4i = r * 64 + (88 * s + 8 * c) / 4;
            float4 a = Wh4[f4i];
            float4 d = Wh4[f4i + 1];
            wr[g * 32 + c * 4 + 0] = f16x2{(_Float16)a.x, (_Float16)a.y};
            wr[g * 32 + c * 4 + 1] = f16x2{(_Float16)a.z, (_Float16)a.w};
            wr[g * 32 + c * 4 + 2] = f16x2{(_Float16)d.x, (_Float16)d.y};
            wr[g * 32 + c * 4 + 3] = f16x2{(_Float16)d.z, (_Float16)d.w};
        }
        #pragma unroll
        for (int c = 0; c < LDSC; ++c) {
            const int k0 = 88 * s + 8 * (REGC + c);
            union { f16x8 v; f16x2 p[4]; } u;
            if (k0 < 256) {
                float4 a = Wh4[r * 64 + k0 / 4];
                float4 d = Wh4[r * 64 + k0 / 4 + 1];
                u.p[0] = f16x2{(_Float16)a.x, (_Float16)a.y};
                u.p[1] = f16x2{(_Float16)a.z, (_Float16)a.w};
                u.p[2] = f16x2{(_Float16)d.x, (_Float16)d.y};
                u.p[3] = f16x2{(_Float16)d.z, (_Float16)d.w};
            } else {
                u.p[0] = f16x2{0, 0}; u.p[1] = f16x2{0, 0};
                u.p[2] = f16x2{0, 0}; u.p[3] = f16x2{0, 0};
            }
            wt8[(g * LDSC + c) * NTHR + tid] = u.v;
        }
    }

    float bias[4] = {0.f, 0.f, 0.f, 0.f};
    if (s == 0) {
        #pragma unroll
        for (int g = 0; g < 4; ++g)
            bias[g] = b_ih[j + g * 256] + b_hh[j + g * 256];
    }

    float cst = 0.f, hval = 0.f;
    if (s == 0) {
        cst  = c0[b * HID + j];
        hval = h0[b * HID + j];
        hbuf[j] = (_Float16)hval;
    }
    if (tid < 8) {
        hbuf[256 + tid]        = (_Float16)0.f;
        hbuf[HPAD + 256 + tid] = (_Float16)0.f;
    }

    for (int t = 0; t < T_STEPS; ++t) {
        __syncthreads();
        const f16x8* hb = (const f16x8*)(hbuf + (t & 1) * HPAD);

        float acc[4] = {0.f, 0.f, 0.f, 0.f};
        if (s != 0) {
            const float4* Wi4 = (const float4*)W_ih;
            const float4* xv4 = (const float4*)(x + ((size_t)t * BATCH + b) * IN)
                                + (s - 1) * 8;
            #pragma unroll
            for (int q = 0; q < 8; ++q) {
                float4 xv = xv4[q];
                #pragma unroll
                for (int g = 0; g < 4; ++g) {
                    float4 wv = Wi4[(j + 256 * g) * 16 + (s - 1) * 8 + q];
                    acc[g] += wv.x * xv.x + wv.y * xv.y + wv.z * xv.z + wv.w * xv.w;
                }
            }
        }
        #pragma unroll
        for (int c = 0; c < REGC; ++c) {
            union { f16x8 v; f16x2 p[4]; } hu;
            hu.v = hb[s * KC + c];
            #pragma unroll
            for (int uu = 0; uu < 4; ++uu) {
                #pragma unroll
                for (int g = 0; g < 4; ++g)
                    acc[g] = fdot2(wr[g * 32 + c * 4 + uu], hu.p[uu], acc[g]);
            }
        }
        #pragma unroll
        for (int c = 0; c < LDSC; ++c) {
            union { f16x8 v; f16x2 p[4]; } hu;
            hu.v = hb[s * KC + REGC + c];
            #pragma unroll
            for (int g = 0; g < 4; ++g) {
                union { f16x8 v; f16x2 p[4]; } wu;
                wu.v = wt8[(g * LDSC + c) * NTHR + tid];
                #pragma unroll
                for (int uu = 0; uu < 4; ++uu)
                    acc[g] = fdot2(wu.p[uu], hu.p[uu], acc[g]);
            }
        }
        if (s != 0)
            psum[(s - 1) * 256 + j] = float4{acc[0], acc[1], acc[2], acc[3]};
        __syncthreads();
        if (s == 0) {
            float4 p1 = psum[j];
            float4 p2 = psum[256 + j];
            float gi = sigf(acc[0] + p1.x + p2.x + bias[0]);
            float gf = sigf(acc[1] + p1.y + p2.y + bias[1]);
            float gg = tanh_fast(acc[2] + p1.z + p2.z + bias[2]);
            float go = sigf(acc[3] + p1.w + p2.w + bias[3]);
            cst  = gf * cst + gi * gg;
            hval = go * tanh_fast(cst);
            hbuf[((t + 1) & 1) * HPAD + j] = (_Float16)hval;
        }
    }

    if (s == 0) esh[j] = hval * W_lin[j];
    __syncthreads();
    if (tid == 0) {
        float z = b_lin[0];
        for (int n = 0; n < 256; ++n) z += esh[n];
        out[b] = sigf(z);
    }
}

extern "C" void kernel_launch(void* const* d_in, const int* in_sizes, int n_in,
                              void* d_out, int out_size, void* d_ws, size_t ws_size,
                              hipStream_t stream) {
    const float* x     = (const float*)d_in[0];
    const float* W_ih  = (const float*)d_in[1];
    const float* W_hh  = (const float*)d_in[2];
    const float* b_ih  = (const float*)d_in[3];
    const float* b_hh  = (const float*)d_in[4];
    const float* W_lin = (const float*)d_in[5];
    const float* b_lin = (const float*)d_in[6];
    const float* h0    = (const float*)d_in[7];
    const float* c0    = (const float*)d_in[8];
    float* out = (float*)d_out;

    const size_t need = (size_t)T_STEPS * BATCH * G4 * sizeof(_Float16); // 128 MB
    if (ws_size >= need) {
        _Float16* xg = (_Float16*)d_ws;
        xg_precompute<<<dim3(BATCH, 32), 256, 0, stream>>>(x, W_ih, b_ih, b_hh, xg);
        lstm_mfma<<<dim3(BATCH), 1024, 0, stream>>>(
            W_hh, W_lin, b_lin, h0, c0, xg, out);
    } else {
        (void)hipFuncSetAttribute((const void*)lstm_fb,
                                  hipFuncAttributeMaxDynamicSharedMemorySize,
                                  SMEM_BYTES);
        lstm_fb<<<dim3(BATCH), NTHR, SMEM_BYTES, stream>>>(
            x, W_ih, W_hh, b_ih, b_hh, W_lin, b_lin, h0, c0, out);
    }
}